// Round 6
// baseline (603.260 us; speedup 1.0000x reference)
//
#include <hip/hip_runtime.h>
#include <hip/hip_bf16.h>

typedef __bf16 v8bf __attribute__((ext_vector_type(8)));
typedef float  v4f  __attribute__((ext_vector_type(4)));

#define NPTS (16*8192)
#define RPB  8192

__device__ __forceinline__ unsigned fenc(float x){
    unsigned u = __float_as_uint(x);
    return (u & 0x80000000u) ? ~u : (u | 0x80000000u);
}
__device__ __forceinline__ float fdec(unsigned u){
    return __uint_as_float((u & 0x80000000u) ? (u ^ 0x80000000u) : ~u);
}

__device__ __forceinline__ v8bf bn_relu8(v8bf v, float4 s0, float4 s1, float4 h0, float4 h1){
    v8bf r;
    r[0] = (__bf16)fmaxf(fmaf((float)v[0], s0.x, h0.x), 0.f);
    r[1] = (__bf16)fmaxf(fmaf((float)v[1], s0.y, h0.y), 0.f);
    r[2] = (__bf16)fmaxf(fmaf((float)v[2], s0.z, h0.z), 0.f);
    r[3] = (__bf16)fmaxf(fmaf((float)v[3], s0.w, h0.w), 0.f);
    r[4] = (__bf16)fmaxf(fmaf((float)v[4], s1.x, h1.x), 0.f);
    r[5] = (__bf16)fmaxf(fmaf((float)v[5], s1.y, h1.y), 0.f);
    r[6] = (__bf16)fmaxf(fmaf((float)v[6], s1.z, h1.z), 0.f);
    r[7] = (__bf16)fmaxf(fmaf((float)v[7], s1.w, h1.w), 0.f);
    return r;
}

// ---------------- stage A
__global__ __launch_bounds__(256) void stats1_k(const float* __restrict__ P,
        const float* __restrict__ W1, const float* __restrict__ b1,
        float* __restrict__ gsum, float* __restrict__ gsumsq)
{
    int tid = threadIdx.x;
    int c = tid & 127, half = tid >> 7;
    float w0 = W1[c*3+0], w1 = W1[c*3+1], w2 = W1[c*3+2], bb = b1[c];
    float s = 0.f, s2 = 0.f;
    int base = blockIdx.x * 512 + half;
    for (int i = 0; i < 256; ++i) {
        int p = base + i*2;
        float x = P[p*3+0], y = P[p*3+1], z = P[p*3+2];
        float v = fmaf(w0,x, fmaf(w1,y, fmaf(w2,z, bb)));
        s += v; s2 = fmaf(v,v,s2);
    }
    __shared__ float ls[256], lq[256];
    ls[tid] = s; lq[tid] = s2;
    __syncthreads();
    if (half == 0) {
        atomicAdd(&gsum[c],   s  + ls[tid+128]);
        atomicAdd(&gsumsq[c], s2 + lq[tid+128]);
    }
}

__global__ void finalize_k(const float* __restrict__ gsum, const float* __restrict__ gsumsq,
        const float* __restrict__ gamma, const float* __restrict__ beta,
        float* __restrict__ scale, float* __restrict__ shift, int C, float invn)
{
    int c = blockIdx.x*blockDim.x + threadIdx.x;
    if (c >= C) return;
    float m   = gsum[c]*invn;
    float var = fmaxf(gsumsq[c]*invn - m*m, 0.f);
    float rs  = rsqrtf(var + 1e-5f);
    float sc  = gamma[c]*rs;
    scale[c] = sc;
    shift[c] = beta[c] - m*sc;
}

__global__ __launch_bounds__(256) void apply1_k(const float* __restrict__ P,
        const float* __restrict__ W1, const float* __restrict__ b1,
        const float* __restrict__ sc, const float* __restrict__ sh,
        __bf16* __restrict__ out)
{
    int tid = threadIdx.x;
    int c = tid & 127, ph = tid >> 7;
    float w0 = W1[c*3+0], w1 = W1[c*3+1], w2 = W1[c*3+2], bb = b1[c];
    float a = sc[c], b_ = sh[c];
    int base = blockIdx.x * 16 + ph;
    #pragma unroll
    for (int i = 0; i < 8; ++i) {
        int p = base + i*2;
        float x = P[p*3+0], y = P[p*3+1], z = P[p*3+2];
        float v = fmaf(w0,x, fmaf(w1,y, fmaf(w2,z, bb)));
        v = fmaxf(fmaf(v, a, b_), 0.f);
        out[(size_t)p*128 + c] = (__bf16)v;
    }
}

__global__ void cvt_k(const float* __restrict__ src, __bf16* __restrict__ dst,
                      int rows, int cols, int sstride, int coff)
{
    int i = blockIdx.x*256 + threadIdx.x;
    if (i >= rows*cols) return;
    int r = i / cols, c = i - r*cols;
    dst[i] = (__bf16)src[(size_t)r*sstride + coff + c];
}

// ---------------- 128x128 MFMA GEMM (stage B) — proven r1/r2 structure
template<bool STORE, bool DOMAX, int LOGNB>
__global__ __launch_bounds__(256, 2) void gemm_k(
        const __bf16* __restrict__ A, const __bf16* __restrict__ Bw,
        int K, int Nw,
        const float* __restrict__ bias, int bias_bstride,
        __bf16* __restrict__ Cout, unsigned* __restrict__ maxenc)
{
    __shared__ __bf16 As[128*64];
    __shared__ __bf16 Bs[128*64];
    const int tid  = threadIdx.x;
    const int lane = tid & 63;
    const int wave = tid >> 6;
    const int wr = wave >> 1, wc = wave & 1;
    const int nwg   = (int)gridDim.x;
    const int chunk = nwg >> 3;
    const int bi    = (int)blockIdx.x;
    const int li    = (bi & 7) * chunk + (bi >> 3);
    const int m0    = (li >> LOGNB) * 128;
    const int n0    = (li & ((1 << LOGNB) - 1)) * 128;
    const int srow = tid >> 3, sslot = tid & 7;

    v4f acc[4][4];
    #pragma unroll
    for (int i=0;i<4;i++)
      #pragma unroll
      for (int j=0;j<4;j++) acc[i][j] = (v4f)(0.0f);

    v8bf ra[4], rb[4];
    #pragma unroll
    for (int i=0;i<4;i++){
        int r = i*32 + srow;
        ra[i] = *(const v8bf*)(A  + (size_t)(m0+r)*K + sslot*8);
        rb[i] = *(const v8bf*)(Bw + (size_t)(n0+r)*K + sslot*8);
    }

    for (int k0 = 0; k0 < K; k0 += 64) {
        __syncthreads();
        #pragma unroll
        for (int i=0;i<4;i++){
            int r = i*32 + srow;
            int p = sslot ^ (r & 7);
            *(v8bf*)(&As[r*64 + p*8]) = ra[i];
            *(v8bf*)(&Bs[r*64 + p*8]) = rb[i];
        }
        __syncthreads();
        if (k0 + 64 < K) {
            #pragma unroll
            for (int i=0;i<4;i++){
                int r = i*32 + srow;
                ra[i] = *(const v8bf*)(A  + (size_t)(m0+r)*K + (k0+64) + sslot*8);
                rb[i] = *(const v8bf*)(Bw + (size_t)(n0+r)*K + (k0+64) + sslot*8);
            }
        }
        #pragma unroll
        for (int kk = 0; kk < 2; ++kk) {
            v8bf af[4], bfr[4];
            #pragma unroll
            for (int i=0;i<4;i++){
                int arow = wr*64 + i*16 + (lane & 15);
                int slog = kk*4 + (lane >> 4);
                af[i]  = *(const v8bf*)(&As[arow*64 + ((slog ^ (arow & 7))<<3)]);
                int brow = wc*64 + i*16 + (lane & 15);
                bfr[i] = *(const v8bf*)(&Bs[brow*64 + ((slog ^ (brow & 7))<<3)]);
            }
            #pragma unroll
            for (int i=0;i<4;i++)
              #pragma unroll
              for (int j=0;j<4;j++)
                acc[i][j] = __builtin_amdgcn_mfma_f32_16x16x32_bf16(af[i], bfr[j], acc[i][j], 0,0,0);
        }
    }

    const int b = m0 / RPB;
    const float* brow_ = bias + (size_t)b * bias_bstride;
    float colmax[4];
    #pragma unroll
    for (int j=0;j<4;j++) colmax[j] = -3.402823466e38f;

    #pragma unroll
    for (int i=0;i<4;i++){
        int rbase = m0 + wr*64 + i*16 + ((lane>>4)<<2);
        #pragma unroll
        for (int j=0;j<4;j++){
            int col = n0 + wc*64 + j*16 + (lane & 15);
            float bv = brow_[col];
            #pragma unroll
            for (int q=0;q<4;q++){
                float v = acc[i][j][q] + bv;
                if constexpr (STORE) Cout[(size_t)(rbase+q)*Nw + col] = (__bf16)v;
                if constexpr (DOMAX) colmax[j] = fmaxf(colmax[j], v);
            }
        }
    }
    if constexpr (DOMAX) {
        #pragma unroll
        for (int j=0;j<4;j++){
            float v = colmax[j];
            v = fmaxf(v, __shfl_xor(v, 16));
            v = fmaxf(v, __shfl_xor(v, 32));
            if (lane < 16) {
                int col = n0 + wc*64 + j*16 + lane;
                atomicMax(&maxenc[(size_t)b*Nw + col], fenc(v));
            }
        }
    }
}

// ---------------- 128x256 8-wave MFMA GEMM (stages C, D) — R2 2-barrier
// structure widened: 48KB LDS -> 2 blocks/CU; BN-staging redundancy halved.
template<bool STORE, bool DOMAX, bool STATS, bool BNA, int LOGNB>
__global__ __launch_bounds__(512, 2) void gemmw_k(
        const __bf16* __restrict__ A, const __bf16* __restrict__ Bw,
        int K, int Nw,
        const float* __restrict__ bias, int bias_bstride,
        __bf16* __restrict__ Cout, unsigned* __restrict__ maxenc,
        float* __restrict__ gsum, float* __restrict__ gsq,
        const float* __restrict__ scA, const float* __restrict__ shA)
{
    __shared__ __bf16 As[128*64];
    __shared__ __bf16 Bs[256*64];
    __shared__ float lstat[2][2][256];
    const int tid  = threadIdx.x;
    const int lane = tid & 63;
    const int wave = tid >> 6;            // 0..7
    const int wr = wave >> 2, wc = wave & 3;
    const int nwg   = (int)gridDim.x;
    const int chunk = nwg >> 3;
    const int bi    = (int)blockIdx.x;
    const int li    = (bi & 7) * chunk + (bi >> 3);
    const int m0    = (li >> LOGNB) * 128;
    const int n0    = (li & ((1 << LOGNB) - 1)) * 256;
    const int srow = tid >> 3;            // 0..63
    const int slot = tid & 7;

    v4f acc[4][4];
    #pragma unroll
    for (int i=0;i<4;i++)
      #pragma unroll
      for (int j=0;j<4;j++) acc[i][j] = (v4f)(0.0f);

    v8bf ra[2], rb[4];
    auto loadAB = [&](int kb){
        float4 s0{}, s1{}, h0{}, h1{};
        if constexpr (BNA) {
            int kk = kb + slot*8;
            s0 = *(const float4*)(scA + kk);
            s1 = *(const float4*)(scA + kk + 4);
            h0 = *(const float4*)(shA + kk);
            h1 = *(const float4*)(shA + kk + 4);
        }
        #pragma unroll
        for (int i=0;i<2;i++){
            int r = i*64 + srow;
            v8bf v = *(const v8bf*)(A + (size_t)(m0+r)*K + kb + slot*8);
            if constexpr (BNA) v = bn_relu8(v, s0, s1, h0, h1);
            ra[i] = v;
        }
        #pragma unroll
        for (int i=0;i<4;i++){
            int r = i*64 + srow;
            rb[i] = *(const v8bf*)(Bw + (size_t)(n0+r)*K + kb + slot*8);
        }
    };

    loadAB(0);

    for (int k0 = 0; k0 < K; k0 += 64) {
        __syncthreads();
        #pragma unroll
        for (int i=0;i<2;i++){
            int r = i*64 + srow;
            int p = slot ^ (r & 7);
            *(v8bf*)(&As[r*64 + p*8]) = ra[i];
        }
        #pragma unroll
        for (int i=0;i<4;i++){
            int r = i*64 + srow;
            int p = slot ^ (r & 7);
            *(v8bf*)(&Bs[r*64 + p*8]) = rb[i];
        }
        __syncthreads();
        if (k0 + 64 < K) loadAB(k0 + 64);
        #pragma unroll
        for (int kk = 0; kk < 2; ++kk) {
            v8bf af[4], bfr[4];
            #pragma unroll
            for (int i=0;i<4;i++){
                int arow = wr*64 + i*16 + (lane & 15);
                int sg = kk*4 + (lane >> 4);
                af[i]  = *(const v8bf*)(&As[arow*64 + ((sg ^ (arow & 7))<<3)]);
                int brow = wc*64 + i*16 + (lane & 15);
                bfr[i] = *(const v8bf*)(&Bs[brow*64 + ((sg ^ (brow & 7))<<3)]);
            }
            #pragma unroll
            for (int i=0;i<4;i++)
              #pragma unroll
              for (int j=0;j<4;j++)
                acc[i][j] = __builtin_amdgcn_mfma_f32_16x16x32_bf16(af[i], bfr[j], acc[i][j], 0,0,0);
        }
    }

    const int b = m0 / RPB;
    const float* brow_ = bias + (size_t)b * bias_bstride;
    float colmax[4], csum[4], csq[4];
    #pragma unroll
    for (int j=0;j<4;j++){ colmax[j] = -3.402823466e38f; csum[j]=0.f; csq[j]=0.f; }

    #pragma unroll
    for (int i=0;i<4;i++){
        int rbase = m0 + wr*64 + i*16 + ((lane>>4)<<2);
        #pragma unroll
        for (int j=0;j<4;j++){
            int col = n0 + wc*64 + j*16 + (lane & 15);
            float bv = brow_[col];
            #pragma unroll
            for (int q=0;q<4;q++){
                float v = acc[i][j][q] + bv;
                if constexpr (STORE) Cout[(size_t)(rbase+q)*Nw + col] = (__bf16)v;
                if constexpr (DOMAX) colmax[j] = fmaxf(colmax[j], v);
                if constexpr (STATS) { csum[j] += v; csq[j] = fmaf(v,v,csq[j]); }
            }
        }
    }
    if constexpr (DOMAX) {
        #pragma unroll
        for (int j=0;j<4;j++){
            float v = colmax[j];
            v = fmaxf(v, __shfl_xor(v, 16));
            v = fmaxf(v, __shfl_xor(v, 32));
            if (lane < 16) {
                int col = n0 + wc*64 + j*16 + lane;
                atomicMax(&maxenc[(size_t)b*Nw + col], fenc(v));
            }
        }
    }
    if constexpr (STATS) {
        #pragma unroll
        for (int j=0;j<4;j++){
            float s = csum[j], q = csq[j];
            s += __shfl_xor(s, 16); s += __shfl_xor(s, 32);
            q += __shfl_xor(q, 16); q += __shfl_xor(q, 32);
            if (lane < 16) {
                int c = wc*64 + j*16 + lane;
                lstat[0][wr][c] = s;
                lstat[1][wr][c] = q;
            }
        }
        __syncthreads();
        if (tid < 256) {
            float s = lstat[0][0][tid] + lstat[0][1][tid];
            float q = lstat[1][0][tid] + lstat[1][1][tid];
            atomicAdd(&gsum[n0 + tid], s);
            atomicAdd(&gsq [n0 + tid], q);
        }
    }
}

// ---------------- bias3[b][d] = b3[d] + fg[b] @ W3[:, :256]^T
__global__ __launch_bounds__(256) void bias3_k(const unsigned* __restrict__ fge,
        const float* __restrict__ W3, const float* __restrict__ b3,
        float* __restrict__ bias3)
{
    int b = blockIdx.x, tid = threadIdx.x;
    __shared__ float fg[256];
    fg[tid] = fdec(fge[b*256 + tid]);
    __syncthreads();
    for (int d = tid; d < 512; d += 256) {
        const float* wrow = W3 + (size_t)d*512;
        float s = b3[d];
        for (int c = 0; c < 256; c += 4) {
            s = fmaf(fg[c+0], wrow[c+0], s);
            s = fmaf(fg[c+1], wrow[c+1], s);
            s = fmaf(fg[c+2], wrow[c+2], s);
            s = fmaf(fg[c+3], wrow[c+3], s);
        }
        bias3[b*512 + d] = s;
    }
}

__global__ void decode_k(const unsigned* __restrict__ enc, float* __restrict__ feat)
{
    int i = blockIdx.x*256 + threadIdx.x;
    int b = i >> 10, c = i & 1023;
    feat[(size_t)b*2048 + c] = fdec(enc[i]);
}

__global__ __launch_bounds__(256) void gates_k(
        const float* __restrict__ Wf, const float* __restrict__ bfv,
        const float* __restrict__ Wi, const float* __restrict__ biv,
        const float* __restrict__ Wo, const float* __restrict__ bov,
        const float* __restrict__ Wc, const float* __restrict__ bcv,
        const float* __restrict__ memv, float* __restrict__ feat)
{
    int tid = threadIdx.x;
    int b = tid & 15;
    int j = blockIdx.x*16 + (tid >> 4);
    const float* x  = feat + (size_t)b*2048;
    const float* rf = Wf + (size_t)j*1024;
    const float* ri = Wi + (size_t)j*1024;
    const float* ro = Wo + (size_t)j*1024;
    const float* rc = Wc + (size_t)j*1024;
    float sf = bfv[j], si = biv[j], so = bov[j], scn = bcv[j];
    for (int c = 0; c < 1024; c += 4) {
        float4 xv = *(const float4*)(x + c);
        float4 a  = *(const float4*)(rf + c);
        sf = fmaf(xv.x,a.x, fmaf(xv.y,a.y, fmaf(xv.z,a.z, fmaf(xv.w,a.w, sf))));
        float4 bq = *(const float4*)(ri + c);
        si = fmaf(xv.x,bq.x, fmaf(xv.y,bq.y, fmaf(xv.z,bq.z, fmaf(xv.w,bq.w, si))));
        float4 cq = *(const float4*)(ro + c);
        so = fmaf(xv.x,cq.x, fmaf(xv.y,cq.y, fmaf(xv.z,cq.z, fmaf(xv.w,cq.w, so))));
        float4 dq = *(const float4*)(rc + c);
        scn= fmaf(xv.x,dq.x, fmaf(xv.y,dq.y, fmaf(xv.z,dq.z, fmaf(xv.w,dq.w, scn))));
    }
    float fg = 1.f/(1.f + expf(-sf));
    float ig = 1.f/(1.f + expf(-si));
    float og = 1.f/(1.f + expf(-so));
    float cd = tanhf(scn);
    float h  = og * tanhf(fmaf(fg, memv[j], ig*cd));
    feat[(size_t)b*2048 + 1024 + j] = h;
}

// ---------------- batched decoder: all 16 batch rows staged in LDS (128KB);
// each W row read ONCE (16 dots amortize it). 8 cols/block (2/wave).
template<bool RELU>
__global__ __launch_bounds__(256) void dec2_k(const float* __restrict__ in,
        const float* __restrict__ W, const float* __restrict__ bias,
        float* __restrict__ out, int N)
{
    __shared__ float xin[16*2048];
    int tid = threadIdx.x;
    for (int i = tid; i < 8192; i += 256)
        *(float4*)&xin[i*4] = *(const float4*)&in[i*4];
    __syncthreads();
    int lane = tid & 63, wv = tid >> 6;
    #pragma unroll
    for (int c = 0; c < 2; ++c) {
        int col = blockIdx.x*8 + wv*2 + c;
        const float* wrow = W + (size_t)col*2048;
        float s[16];
        #pragma unroll
        for (int b=0;b<16;b++) s[b]=0.f;
        #pragma unroll
        for (int it = 0; it < 8; ++it) {
            int k = it*256 + lane*4;
            float4 w4 = *(const float4*)(wrow + k);
            #pragma unroll
            for (int b=0;b<16;b++){
                const float* xb = &xin[b*2048 + k];
                s[b] = fmaf(w4.x, xb[0], fmaf(w4.y, xb[1], fmaf(w4.z, xb[2], fmaf(w4.w, xb[3], s[b]))));
            }
        }
        #pragma unroll
        for (int off=32; off; off>>=1){
            #pragma unroll
            for (int b=0;b<16;b++) s[b] += __shfl_xor(s[b], off);
        }
        if (lane == 0) {
            float bv = bias[col];
            #pragma unroll
            for (int b=0;b<16;b++){
                float v = s[b] + bv;
                if (RELU) v = fmaxf(v, 0.f);
                out[(size_t)b*N + col] = v;
            }
        }
    }
}

extern "C" void kernel_launch(void* const* d_in, const int* in_sizes, int n_in,
                              void* d_out, int out_size, void* d_ws, size_t ws_size,
                              hipStream_t stream)
{
    (void)in_sizes; (void)n_in; (void)out_size; (void)ws_size;
    const float* partial = (const float*)d_in[0];
    const float* W1 = (const float*)d_in[1];
    const float* b1 = (const float*)d_in[2];
    const float* g1 = (const float*)d_in[3];
    const float* be1= (const float*)d_in[4];
    const float* W2 = (const float*)d_in[5];
    const float* b2 = (const float*)d_in[6];
    const float* W3 = (const float*)d_in[7];
    const float* b3 = (const float*)d_in[8];
    const float* g2 = (const float*)d_in[9];
    const float* be2= (const float*)d_in[10];
    const float* W4 = (const float*)d_in[11];
    const float* b4 = (const float*)d_in[12];
    const float* Wf = (const float*)d_in[13];
    const float* bfv= (const float*)d_in[14];
    const float* Wi = (const float*)d_in[15];
    const float* biv= (const float*)d_in[16];
    const float* Wo = (const float*)d_in[17];
    const float* bov= (const float*)d_in[18];
    const float* Wc = (const float*)d_in[19];
    const float* bcv= (const float*)d_in[20];
    const float* memv=(const float*)d_in[21];
    const float* D1w= (const float*)d_in[22];
    const float* D1b= (const float*)d_in[23];
    const float* D2w= (const float*)d_in[24];
    const float* D2b= (const float*)d_in[25];
    const float* D3w= (const float*)d_in[26];
    const float* D3b= (const float*)d_in[27];
    const float* D4w= (const float*)d_in[28];
    const float* D4b= (const float*)d_in[29];

    char* w = (char*)d_ws;
    size_t off = 0;
    auto alloc = [&](size_t bytes) -> void* {
        void* p = w + off; off += (bytes + 255) & ~(size_t)255; return p;
    };
    __bf16* y1bn = (__bf16*)alloc((size_t)NPTS*128*2);
    __bf16* f2   = (__bf16*)alloc((size_t)NPTS*256*2);
    __bf16* y3   = (__bf16*)alloc((size_t)NPTS*512*2);   // PRE-BN y3
    __bf16* W2b  = (__bf16*)alloc(256*128*2);
    __bf16* W3bb = (__bf16*)alloc(512*256*2);
    __bf16* W4b  = (__bf16*)alloc(1024*512*2);
    char* accbase = (char*)(w + off);
    float* gsum1    = (float*)alloc(128*4);
    float* gsumsq1  = (float*)alloc(128*4);
    float* gsum3    = (float*)alloc(512*4);
    float* gsumsq3  = (float*)alloc(512*4);
    unsigned* fg_enc    = (unsigned*)alloc(16*256*4);
    unsigned* featg_enc = (unsigned*)alloc(16*1024*4);
    size_t accbytes = (size_t)((w + off) - accbase);
    float* scale1 = (float*)alloc(128*4);
    float* shift1 = (float*)alloc(128*4);
    float* scale3 = (float*)alloc(512*4);
    float* shift3 = (float*)alloc(512*4);
    float* bias3  = (float*)alloc(16*512*4);
    float* feat   = (float*)alloc(16*2048*4);
    float* z1     = (float*)alloc(16*2048*4);
    float* z2     = (float*)alloc(16*2048*4);
    float* z3     = (float*)alloc(16*2048*4);

    hipMemsetAsync(accbase, 0, accbytes, stream);

    cvt_k<<<dim3(128), 256, 0, stream>>>(W2, W2b, 256, 128, 128, 0);
    cvt_k<<<dim3(512), 256, 0, stream>>>(W3, W3bb, 512, 256, 512, 256);
    cvt_k<<<dim3(2048),256, 0, stream>>>(W4, W4b, 1024, 512, 512, 0);

    stats1_k<<<dim3(256), 256, 0, stream>>>(partial, W1, b1, gsum1, gsumsq1);
    finalize_k<<<dim3(1), 128, 0, stream>>>(gsum1, gsumsq1, g1, be1, scale1, shift1, 128, 1.f/NPTS);
    apply1_k<<<dim3(8192), 256, 0, stream>>>(partial, W1, b1, scale1, shift1, y1bn);

    // stage B: f2 = y1bn @ W2^T + b2 ; fg = per-batch colmax  (128^2 kernel)
    gemm_k<true,true,1><<<dim3(2048), 256, 0, stream>>>(
        y1bn, W2b, 128, 256, b2, 0, f2, fg_enc);

    bias3_k<<<dim3(16), 256, 0, stream>>>(fg_enc, W3, b3, bias3);

    // stage C: y3 = f2 @ W3[:,256:]^T + bias3[b]  (+ fused BN2 stats), 128x256 tiles
    gemmw_k<true,false,true,false,1><<<dim3(2048), 512, 0, stream>>>(
        f2, W3bb, 256, 512, bias3, 512, y3, nullptr, gsum3, gsumsq3, nullptr, nullptr);

    finalize_k<<<dim3(2), 256, 0, stream>>>(gsum3, gsumsq3, g2, be2, scale3, shift3, 512, 1.f/NPTS);

    // stage D: feat_global = per-batch colmax( relu(bn2(y3)) @ W4^T + b4 ), 128x256 tiles
    gemmw_k<false,true,false,true,2><<<dim3(4096), 512, 0, stream>>>(
        y3, W4b, 512, 1024, b4, 0, nullptr, featg_enc, nullptr, nullptr, scale3, shift3);

    decode_k<<<dim3(64), 256, 0, stream>>>(featg_enc, feat);
    gates_k<<<dim3(64), 256, 0, stream>>>(Wf,bfv, Wi,biv, Wo,bov, Wc,bcv, memv, feat);

    // decoder: weight-read-once batched GEMV
    dec2_k<true ><<<dim3(256), 256, 0, stream>>>(feat, D1w, D1b, z1, 2048);
    dec2_k<true ><<<dim3(256), 256, 0, stream>>>(z1,   D2w, D2b, z2, 2048);
    dec2_k<true ><<<dim3(256), 256, 0, stream>>>(z2,   D3w, D3b, z3, 2048);
    dec2_k<false><<<dim3(768), 256, 0, stream>>>(z3,   D4w, D4b, (float*)d_out, 6144);
}

// Round 7
// 507.368 us; speedup vs baseline: 1.1890x; 1.1890x over previous
//
#include <hip/hip_runtime.h>
#include <hip/hip_bf16.h>

typedef __bf16 v8bf __attribute__((ext_vector_type(8)));
typedef float  v4f  __attribute__((ext_vector_type(4)));

#define NPTS (16*8192)
#define RPB  8192

__device__ __forceinline__ unsigned fenc(float x){
    unsigned u = __float_as_uint(x);
    return (u & 0x80000000u) ? ~u : (u | 0x80000000u);
}
__device__ __forceinline__ float fdec(unsigned u){
    return __uint_as_float((u & 0x80000000u) ? (u ^ 0x80000000u) : ~u);
}

__device__ __forceinline__ v8bf bn_relu8(v8bf v, float4 s0, float4 s1, float4 h0, float4 h1){
    v8bf r;
    r[0] = (__bf16)fmaxf(fmaf((float)v[0], s0.x, h0.x), 0.f);
    r[1] = (__bf16)fmaxf(fmaf((float)v[1], s0.y, h0.y), 0.f);
    r[2] = (__bf16)fmaxf(fmaf((float)v[2], s0.z, h0.z), 0.f);
    r[3] = (__bf16)fmaxf(fmaf((float)v[3], s0.w, h0.w), 0.f);
    r[4] = (__bf16)fmaxf(fmaf((float)v[4], s1.x, h1.x), 0.f);
    r[5] = (__bf16)fmaxf(fmaf((float)v[5], s1.y, h1.y), 0.f);
    r[6] = (__bf16)fmaxf(fmaf((float)v[6], s1.z, h1.z), 0.f);
    r[7] = (__bf16)fmaxf(fmaf((float)v[7], s1.w, h1.w), 0.f);
    return r;
}

// ---------------- stage A: BN1 stats over y1 = partial@W1^T + b1 (recomputed, K=3)
__global__ __launch_bounds__(256) void stats1_k(const float* __restrict__ P,
        const float* __restrict__ W1, const float* __restrict__ b1,
        float* __restrict__ gsum, float* __restrict__ gsumsq)
{
    int tid = threadIdx.x;
    int c = tid & 127, half = tid >> 7;
    float w0 = W1[c*3+0], w1 = W1[c*3+1], w2 = W1[c*3+2], bb = b1[c];
    float s = 0.f, s2 = 0.f;
    int base = blockIdx.x * 512 + half;
    for (int i = 0; i < 256; ++i) {
        int p = base + i*2;
        float x = P[p*3+0], y = P[p*3+1], z = P[p*3+2];
        float v = fmaf(w0,x, fmaf(w1,y, fmaf(w2,z, bb)));
        s += v; s2 = fmaf(v,v,s2);
    }
    __shared__ float ls[256], lq[256];
    ls[tid] = s; lq[tid] = s2;
    __syncthreads();
    if (half == 0) {
        atomicAdd(&gsum[c],   s  + ls[tid+128]);
        atomicAdd(&gsumsq[c], s2 + lq[tid+128]);
    }
}

__global__ void finalize_k(const float* __restrict__ gsum, const float* __restrict__ gsumsq,
        const float* __restrict__ gamma, const float* __restrict__ beta,
        float* __restrict__ scale, float* __restrict__ shift, int C, float invn)
{
    int c = blockIdx.x*blockDim.x + threadIdx.x;
    if (c >= C) return;
    float m   = gsum[c]*invn;
    float var = fmaxf(gsumsq[c]*invn - m*m, 0.f);
    float rs  = rsqrtf(var + 1e-5f);
    float sc  = gamma[c]*rs;
    scale[c] = sc;
    shift[c] = beta[c] - m*sc;
}

__global__ __launch_bounds__(256) void apply1_k(const float* __restrict__ P,
        const float* __restrict__ W1, const float* __restrict__ b1,
        const float* __restrict__ sc, const float* __restrict__ sh,
        __bf16* __restrict__ out)
{
    int tid = threadIdx.x;
    int c = tid & 127, ph = tid >> 7;
    float w0 = W1[c*3+0], w1 = W1[c*3+1], w2 = W1[c*3+2], bb = b1[c];
    float a = sc[c], b_ = sh[c];
    int base = blockIdx.x * 16 + ph;
    #pragma unroll
    for (int i = 0; i < 8; ++i) {
        int p = base + i*2;
        float x = P[p*3+0], y = P[p*3+1], z = P[p*3+2];
        float v = fmaf(w0,x, fmaf(w1,y, fmaf(w2,z, bb)));
        v = fmaxf(fmaf(v, a, b_), 0.f);
        out[(size_t)p*128 + c] = (__bf16)v;
    }
}

__global__ void cvt_k(const float* __restrict__ src, __bf16* __restrict__ dst,
                      int rows, int cols, int sstride, int coff)
{
    int i = blockIdx.x*256 + threadIdx.x;
    if (i >= rows*cols) return;
    int r = i / cols, c = i - r*cols;
    dst[i] = (__bf16)src[(size_t)r*sstride + coff + c];
}

// ---------------- 128x128 MFMA GEMM — R2-proven structure (all GEMM stages)
// XCD-chunked 1-D grid swizzle; optional fused BN-apply on A (BNA), fused
// column stats (STATS), per-batch colmax (DOMAX).
template<bool STORE, bool DOMAX, bool STATS, bool BNA, int LOGNB>
__global__ __launch_bounds__(256, 2) void gemm_k(
        const __bf16* __restrict__ A, const __bf16* __restrict__ Bw,
        int K, int Nw,
        const float* __restrict__ bias, int bias_bstride,
        __bf16* __restrict__ Cout, unsigned* __restrict__ maxenc,
        float* __restrict__ gsum, float* __restrict__ gsq,
        const float* __restrict__ scA, const float* __restrict__ shA)
{
    __shared__ __bf16 As[128*64];
    __shared__ __bf16 Bs[128*64];
    __shared__ float lstat[2][2][128];

    const int tid  = threadIdx.x;
    const int lane = tid & 63;
    const int wave = tid >> 6;
    const int wr = wave >> 1, wc = wave & 1;
    const int nwg   = (int)gridDim.x;
    const int chunk = nwg >> 3;
    const int bi    = (int)blockIdx.x;
    const int li    = (bi & 7) * chunk + (bi >> 3);
    const int m0    = (li >> LOGNB) * 128;
    const int n0    = (li & ((1 << LOGNB) - 1)) * 128;
    const int srow = tid >> 3, sslot = tid & 7;

    v4f acc[4][4];
    #pragma unroll
    for (int i=0;i<4;i++)
      #pragma unroll
      for (int j=0;j<4;j++) acc[i][j] = (v4f)(0.0f);

    v8bf ra[4], rb[4];
    auto loadAB = [&](int kb){
        float4 s0{}, s1{}, h0{}, h1{};
        if constexpr (BNA) {
            int kk = kb + sslot*8;
            s0 = *(const float4*)(scA + kk);
            s1 = *(const float4*)(scA + kk + 4);
            h0 = *(const float4*)(shA + kk);
            h1 = *(const float4*)(shA + kk + 4);
        }
        #pragma unroll
        for (int i=0;i<4;i++){
            int r = i*32 + srow;
            v8bf v = *(const v8bf*)(A + (size_t)(m0+r)*K + kb + sslot*8);
            if constexpr (BNA) v = bn_relu8(v, s0, s1, h0, h1);
            ra[i] = v;
            rb[i] = *(const v8bf*)(Bw + (size_t)(n0+r)*K + kb + sslot*8);
        }
    };

    loadAB(0);

    for (int k0 = 0; k0 < K; k0 += 64) {
        __syncthreads();
        #pragma unroll
        for (int i=0;i<4;i++){
            int r = i*32 + srow;
            int p = sslot ^ (r & 7);               // swizzled LDS slot
            *(v8bf*)(&As[r*64 + p*8]) = ra[i];
            *(v8bf*)(&Bs[r*64 + p*8]) = rb[i];
        }
        __syncthreads();
        if (k0 + 64 < K) loadAB(k0 + 64);
        #pragma unroll
        for (int kk = 0; kk < 2; ++kk) {
            v8bf af[4], bfr[4];
            #pragma unroll
            for (int i=0;i<4;i++){
                int arow = wr*64 + i*16 + (lane & 15);
                int slog = kk*4 + (lane >> 4);
                af[i]  = *(const v8bf*)(&As[arow*64 + ((slog ^ (arow & 7))<<3)]);
                int brow = wc*64 + i*16 + (lane & 15);
                bfr[i] = *(const v8bf*)(&Bs[brow*64 + ((slog ^ (brow & 7))<<3)]);
            }
            #pragma unroll
            for (int i=0;i<4;i++)
              #pragma unroll
              for (int j=0;j<4;j++)
                acc[i][j] = __builtin_amdgcn_mfma_f32_16x16x32_bf16(af[i], bfr[j], acc[i][j], 0,0,0);
        }
    }

    const int b = m0 / RPB;
    const float* brow_ = bias + (size_t)b * bias_bstride;
    float colmax[4], csum[4], csq[4];
    #pragma unroll
    for (int j=0;j<4;j++){ colmax[j] = -3.402823466e38f; csum[j]=0.f; csq[j]=0.f; }

    #pragma unroll
    for (int i=0;i<4;i++){
        int rbase = m0 + wr*64 + i*16 + ((lane>>4)<<2);
        #pragma unroll
        for (int j=0;j<4;j++){
            int col = n0 + wc*64 + j*16 + (lane & 15);
            float bv = brow_[col];
            #pragma unroll
            for (int q=0;q<4;q++){
                float v = acc[i][j][q] + bv;
                if constexpr (STORE) Cout[(size_t)(rbase+q)*Nw + col] = (__bf16)v;
                if constexpr (DOMAX) colmax[j] = fmaxf(colmax[j], v);
                if constexpr (STATS) { csum[j] += v; csq[j] = fmaf(v,v,csq[j]); }
            }
        }
    }
    if constexpr (DOMAX) {
        #pragma unroll
        for (int j=0;j<4;j++){
            float v = colmax[j];
            v = fmaxf(v, __shfl_xor(v, 16));
            v = fmaxf(v, __shfl_xor(v, 32));
            if (lane < 16) {
                int col = n0 + wc*64 + j*16 + lane;
                atomicMax(&maxenc[(size_t)b*Nw + col], fenc(v));
            }
        }
    }
    if constexpr (STATS) {
        #pragma unroll
        for (int j=0;j<4;j++){
            float s = csum[j], q = csq[j];
            s += __shfl_xor(s, 16); s += __shfl_xor(s, 32);
            q += __shfl_xor(q, 16); q += __shfl_xor(q, 32);
            if (lane < 16) {
                int c = wc*64 + j*16 + lane;
                lstat[0][wr][c] = s;
                lstat[1][wr][c] = q;
            }
        }
        __syncthreads();
        if (tid < 128) {
            float s = lstat[0][0][tid] + lstat[0][1][tid];
            float q = lstat[1][0][tid] + lstat[1][1][tid];
            atomicAdd(&gsum[n0 + tid], s);
            atomicAdd(&gsq [n0 + tid], q);
        }
    }
}

// ---------------- bias3[b][d] = b3[d] + fg[b] @ W3[:, :256]^T
__global__ __launch_bounds__(256) void bias3_k(const unsigned* __restrict__ fge,
        const float* __restrict__ W3, const float* __restrict__ b3,
        float* __restrict__ bias3)
{
    int b = blockIdx.x, tid = threadIdx.x;
    __shared__ float fg[256];
    fg[tid] = fdec(fge[b*256 + tid]);
    __syncthreads();
    for (int d = tid; d < 512; d += 256) {
        const float* wrow = W3 + (size_t)d*512;
        float s = b3[d];
        for (int c = 0; c < 256; c += 4) {
            s = fmaf(fg[c+0], wrow[c+0], s);
            s = fmaf(fg[c+1], wrow[c+1], s);
            s = fmaf(fg[c+2], wrow[c+2], s);
            s = fmaf(fg[c+3], wrow[c+3], s);
        }
        bias3[b*512 + d] = s;
    }
}

__global__ void decode_k(const unsigned* __restrict__ enc, float* __restrict__ feat)
{
    int i = blockIdx.x*256 + threadIdx.x;
    int b = i >> 10, c = i & 1023;
    feat[(size_t)b*2048 + c] = fdec(enc[i]);
}

__global__ __launch_bounds__(256) void gates_k(
        const float* __restrict__ Wf, const float* __restrict__ bfv,
        const float* __restrict__ Wi, const float* __restrict__ biv,
        const float* __restrict__ Wo, const float* __restrict__ bov,
        const float* __restrict__ Wc, const float* __restrict__ bcv,
        const float* __restrict__ memv, float* __restrict__ feat)
{
    int tid = threadIdx.x;
    int b = tid & 15;
    int j = blockIdx.x*16 + (tid >> 4);
    const float* x  = feat + (size_t)b*2048;
    const float* rf = Wf + (size_t)j*1024;
    const float* ri = Wi + (size_t)j*1024;
    const float* ro = Wo + (size_t)j*1024;
    const float* rc = Wc + (size_t)j*1024;
    float sf = bfv[j], si = biv[j], so = bov[j], scn = bcv[j];
    for (int c = 0; c < 1024; c += 4) {
        float4 xv = *(const float4*)(x + c);
        float4 a  = *(const float4*)(rf + c);
        sf = fmaf(xv.x,a.x, fmaf(xv.y,a.y, fmaf(xv.z,a.z, fmaf(xv.w,a.w, sf))));
        float4 bq = *(const float4*)(ri + c);
        si = fmaf(xv.x,bq.x, fmaf(xv.y,bq.y, fmaf(xv.z,bq.z, fmaf(xv.w,bq.w, si))));
        float4 cq = *(const float4*)(ro + c);
        so = fmaf(xv.x,cq.x, fmaf(xv.y,cq.y, fmaf(xv.z,cq.z, fmaf(xv.w,cq.w, so))));
        float4 dq = *(const float4*)(rc + c);
        scn= fmaf(xv.x,dq.x, fmaf(xv.y,dq.y, fmaf(xv.z,dq.z, fmaf(xv.w,dq.w, scn))));
    }
    float fg = 1.f/(1.f + expf(-sf));
    float ig = 1.f/(1.f + expf(-si));
    float og = 1.f/(1.f + expf(-so));
    float cd = tanhf(scn);
    float h  = og * tanhf(fmaf(fg, memv[j], ig*cd));
    feat[(size_t)b*2048 + 1024 + j] = h;
}

// ---------------- batched decoder: all 16 batch rows staged in LDS (128KB);
// each W row read ONCE (16 dots amortize it). 8 cols/block (2/wave).
template<bool RELU>
__global__ __launch_bounds__(256) void dec2_k(const float* __restrict__ in,
        const float* __restrict__ W, const float* __restrict__ bias,
        float* __restrict__ out, int N)
{
    __shared__ float xin[16*2048];
    int tid = threadIdx.x;
    for (int i = tid; i < 8192; i += 256)
        *(float4*)&xin[i*4] = *(const float4*)&in[i*4];
    __syncthreads();
    int lane = tid & 63, wv = tid >> 6;
    #pragma unroll
    for (int c = 0; c < 2; ++c) {
        int col = blockIdx.x*8 + wv*2 + c;
        const float* wrow = W + (size_t)col*2048;
        float s[16];
        #pragma unroll
        for (int b=0;b<16;b++) s[b]=0.f;
        #pragma unroll
        for (int it = 0; it < 8; ++it) {
            int k = it*256 + lane*4;
            float4 w4 = *(const float4*)(wrow + k);
            #pragma unroll
            for (int b=0;b<16;b++){
                const float* xb = &xin[b*2048 + k];
                s[b] = fmaf(w4.x, xb[0], fmaf(w4.y, xb[1], fmaf(w4.z, xb[2], fmaf(w4.w, xb[3], s[b]))));
            }
        }
        #pragma unroll
        for (int off=32; off; off>>=1){
            #pragma unroll
            for (int b=0;b<16;b++) s[b] += __shfl_xor(s[b], off);
        }
        if (lane == 0) {
            float bv = bias[col];
            #pragma unroll
            for (int b=0;b<16;b++){
                float v = s[b] + bv;
                if (RELU) v = fmaxf(v, 0.f);
                out[(size_t)b*N + col] = v;
            }
        }
    }
}

extern "C" void kernel_launch(void* const* d_in, const int* in_sizes, int n_in,
                              void* d_out, int out_size, void* d_ws, size_t ws_size,
                              hipStream_t stream)
{
    (void)in_sizes; (void)n_in; (void)out_size; (void)ws_size;
    const float* partial = (const float*)d_in[0];
    const float* W1 = (const float*)d_in[1];
    const float* b1 = (const float*)d_in[2];
    const float* g1 = (const float*)d_in[3];
    const float* be1= (const float*)d_in[4];
    const float* W2 = (const float*)d_in[5];
    const float* b2 = (const float*)d_in[6];
    const float* W3 = (const float*)d_in[7];
    const float* b3 = (const float*)d_in[8];
    const float* g2 = (const float*)d_in[9];
    const float* be2= (const float*)d_in[10];
    const float* W4 = (const float*)d_in[11];
    const float* b4 = (const float*)d_in[12];
    const float* Wf = (const float*)d_in[13];
    const float* bfv= (const float*)d_in[14];
    const float* Wi = (const float*)d_in[15];
    const float* biv= (const float*)d_in[16];
    const float* Wo = (const float*)d_in[17];
    const float* bov= (const float*)d_in[18];
    const float* Wc = (const float*)d_in[19];
    const float* bcv= (const float*)d_in[20];
    const float* memv=(const float*)d_in[21];
    const float* D1w= (const float*)d_in[22];
    const float* D1b= (const float*)d_in[23];
    const float* D2w= (const float*)d_in[24];
    const float* D2b= (const float*)d_in[25];
    const float* D3w= (const float*)d_in[26];
    const float* D3b= (const float*)d_in[27];
    const float* D4w= (const float*)d_in[28];
    const float* D4b= (const float*)d_in[29];

    char* w = (char*)d_ws;
    size_t off = 0;
    auto alloc = [&](size_t bytes) -> void* {
        void* p = w + off; off += (bytes + 255) & ~(size_t)255; return p;
    };
    __bf16* y1bn = (__bf16*)alloc((size_t)NPTS*128*2);
    __bf16* f2   = (__bf16*)alloc((size_t)NPTS*256*2);
    __bf16* y3   = (__bf16*)alloc((size_t)NPTS*512*2);   // PRE-BN y3
    __bf16* W2b  = (__bf16*)alloc(256*128*2);
    __bf16* W3bb = (__bf16*)alloc(512*256*2);
    __bf16* W4b  = (__bf16*)alloc(1024*512*2);
    char* accbase = (char*)(w + off);
    float* gsum1    = (float*)alloc(128*4);
    float* gsumsq1  = (float*)alloc(128*4);
    float* gsum3    = (float*)alloc(512*4);
    float* gsumsq3  = (float*)alloc(512*4);
    unsigned* fg_enc    = (unsigned*)alloc(16*256*4);
    unsigned* featg_enc = (unsigned*)alloc(16*1024*4);
    size_t accbytes = (size_t)((w + off) - accbase);
    float* scale1 = (float*)alloc(128*4);
    float* shift1 = (float*)alloc(128*4);
    float* scale3 = (float*)alloc(512*4);
    float* shift3 = (float*)alloc(512*4);
    float* bias3  = (float*)alloc(16*512*4);
    float* feat   = (float*)alloc(16*2048*4);
    float* z1     = (float*)alloc(16*2048*4);
    float* z2     = (float*)alloc(16*2048*4);
    float* z3     = (float*)alloc(16*2048*4);

    hipMemsetAsync(accbase, 0, accbytes, stream);

    cvt_k<<<dim3(128), 256, 0, stream>>>(W2, W2b, 256, 128, 128, 0);
    cvt_k<<<dim3(512), 256, 0, stream>>>(W3, W3bb, 512, 256, 512, 256);
    cvt_k<<<dim3(2048),256, 0, stream>>>(W4, W4b, 1024, 512, 512, 0);

    stats1_k<<<dim3(256), 256, 0, stream>>>(partial, W1, b1, gsum1, gsumsq1);
    finalize_k<<<dim3(1), 128, 0, stream>>>(gsum1, gsumsq1, g1, be1, scale1, shift1, 128, 1.f/NPTS);
    apply1_k<<<dim3(8192), 256, 0, stream>>>(partial, W1, b1, scale1, shift1, y1bn);

    // stage B: f2 = y1bn @ W2^T + b2 ; fg = per-batch colmax
    gemm_k<true,true,false,false,1><<<dim3(2048), 256, 0, stream>>>(
        y1bn, W2b, 128, 256, b2, 0, f2, fg_enc, nullptr, nullptr, nullptr, nullptr);

    bias3_k<<<dim3(16), 256, 0, stream>>>(fg_enc, W3, b3, bias3);

    // stage C: y3 = f2 @ W3[:,256:]^T + bias3[b]  (+ fused BN2 stats)
    gemm_k<true,false,true,false,2><<<dim3(4096), 256, 0, stream>>>(
        f2, W3bb, 256, 512, bias3, 512, y3, nullptr, gsum3, gsumsq3, nullptr, nullptr);

    finalize_k<<<dim3(2), 256, 0, stream>>>(gsum3, gsumsq3, g2, be2, scale3, shift3, 512, 1.f/NPTS);

    // stage D: feat_global = per-batch colmax( relu(bn2(y3)) @ W4^T + b4 )
    gemm_k<false,true,false,true,3><<<dim3(8192), 256, 0, stream>>>(
        y3, W4b, 512, 1024, b4, 0, nullptr, featg_enc, nullptr, nullptr, scale3, shift3);

    decode_k<<<dim3(64), 256, 0, stream>>>(featg_enc, feat);
    gates_k<<<dim3(64), 256, 0, stream>>>(Wf,bfv, Wi,biv, Wo,bov, Wc,bcv, memv, feat);

    // decoder: weight-read-once batched GEMV
    dec2_k<true ><<<dim3(256), 256, 0, stream>>>(feat, D1w, D1b, z1, 2048);
    dec2_k<true ><<<dim3(256), 256, 0, stream>>>(z1,   D2w, D2b, z2, 2048);
    dec2_k<true ><<<dim3(256), 256, 0, stream>>>(z2,   D3w, D3b, z3, 2048);
    dec2_k<false><<<dim3(768), 256, 0, stream>>>(z3,   D4w, D4b, (float*)d_out, 6144);
}

// Round 8
// 502.752 us; speedup vs baseline: 1.1999x; 1.0092x over previous
//
#include <hip/hip_runtime.h>
#include <hip/hip_bf16.h>

typedef __bf16 v8bf __attribute__((ext_vector_type(8)));
typedef float  v4f  __attribute__((ext_vector_type(4)));

#define NPTS (16*8192)
#define RPB  8192

__device__ __forceinline__ unsigned fenc(float x){
    unsigned u = __float_as_uint(x);
    return (u & 0x80000000u) ? ~u : (u | 0x80000000u);
}
__device__ __forceinline__ float fdec(unsigned u){
    return __uint_as_float((u & 0x80000000u) ? (u ^ 0x80000000u) : ~u);
}

__device__ __forceinline__ v8bf bn_relu8(v8bf v, float4 s0, float4 s1, float4 h0, float4 h1){
    v8bf r;
    r[0] = (__bf16)fmaxf(fmaf((float)v[0], s0.x, h0.x), 0.f);
    r[1] = (__bf16)fmaxf(fmaf((float)v[1], s0.y, h0.y), 0.f);
    r[2] = (__bf16)fmaxf(fmaf((float)v[2], s0.z, h0.z), 0.f);
    r[3] = (__bf16)fmaxf(fmaf((float)v[3], s0.w, h0.w), 0.f);
    r[4] = (__bf16)fmaxf(fmaf((float)v[4], s1.x, h1.x), 0.f);
    r[5] = (__bf16)fmaxf(fmaf((float)v[5], s1.y, h1.y), 0.f);
    r[6] = (__bf16)fmaxf(fmaf((float)v[6], s1.z, h1.z), 0.f);
    r[7] = (__bf16)fmaxf(fmaf((float)v[7], s1.w, h1.w), 0.f);
    return r;
}

// ---------------- stage A
__global__ __launch_bounds__(256) void stats1_k(const float* __restrict__ P,
        const float* __restrict__ W1, const float* __restrict__ b1,
        float* __restrict__ gsum, float* __restrict__ gsumsq)
{
    int tid = threadIdx.x;
    int c = tid & 127, half = tid >> 7;
    float w0 = W1[c*3+0], w1 = W1[c*3+1], w2 = W1[c*3+2], bb = b1[c];
    float s = 0.f, s2 = 0.f;
    int base = blockIdx.x * 512 + half;
    for (int i = 0; i < 256; ++i) {
        int p = base + i*2;
        float x = P[p*3+0], y = P[p*3+1], z = P[p*3+2];
        float v = fmaf(w0,x, fmaf(w1,y, fmaf(w2,z, bb)));
        s += v; s2 = fmaf(v,v,s2);
    }
    __shared__ float ls[256], lq[256];
    ls[tid] = s; lq[tid] = s2;
    __syncthreads();
    if (half == 0) {
        atomicAdd(&gsum[c],   s  + ls[tid+128]);
        atomicAdd(&gsumsq[c], s2 + lq[tid+128]);
    }
}

__global__ void finalize_k(const float* __restrict__ gsum, const float* __restrict__ gsumsq,
        const float* __restrict__ gamma, const float* __restrict__ beta,
        float* __restrict__ scale, float* __restrict__ shift, int C, float invn)
{
    int c = blockIdx.x*blockDim.x + threadIdx.x;
    if (c >= C) return;
    float m   = gsum[c]*invn;
    float var = fmaxf(gsumsq[c]*invn - m*m, 0.f);
    float rs  = rsqrtf(var + 1e-5f);
    float sc  = gamma[c]*rs;
    scale[c] = sc;
    shift[c] = beta[c] - m*sc;
}

__global__ __launch_bounds__(256) void apply1_k(const float* __restrict__ P,
        const float* __restrict__ W1, const float* __restrict__ b1,
        const float* __restrict__ sc, const float* __restrict__ sh,
        __bf16* __restrict__ out)
{
    int tid = threadIdx.x;
    int c = tid & 127, ph = tid >> 7;
    float w0 = W1[c*3+0], w1 = W1[c*3+1], w2 = W1[c*3+2], bb = b1[c];
    float a = sc[c], b_ = sh[c];
    int base = blockIdx.x * 16 + ph;
    #pragma unroll
    for (int i = 0; i < 8; ++i) {
        int p = base + i*2;
        float x = P[p*3+0], y = P[p*3+1], z = P[p*3+2];
        float v = fmaf(w0,x, fmaf(w1,y, fmaf(w2,z, bb)));
        v = fmaxf(fmaf(v, a, b_), 0.f);
        out[(size_t)p*128 + c] = (__bf16)v;
    }
}

__global__ void cvt_k(const float* __restrict__ src, __bf16* __restrict__ dst,
                      int rows, int cols, int sstride, int coff)
{
    int i = blockIdx.x*256 + threadIdx.x;
    if (i >= rows*cols) return;
    int r = i / cols, c = i - r*cols;
    dst[i] = (__bf16)src[(size_t)r*sstride + coff + c];
}

// ---------------- 128x256 MFMA GEMM — R2 sync structure, N-tile widened to 256.
// 4 waves (2x2), each wave 64 rows x 128 cols (acc[4][8]); BN redundancy and
// ds_read/MFMA ratio both reduced vs 128^2. XCD-chunked 1-D swizzle.
template<bool STORE, bool DOMAX, bool STATS, bool BNA, int LOGNB>
__global__ __launch_bounds__(256, 2) void gemm_k(
        const __bf16* __restrict__ A, const __bf16* __restrict__ Bw,
        int K, int Nw,
        const float* __restrict__ bias, int bias_bstride,
        __bf16* __restrict__ Cout, unsigned* __restrict__ maxenc,
        float* __restrict__ gsum, float* __restrict__ gsq,
        const float* __restrict__ scA, const float* __restrict__ shA)
{
    __shared__ __bf16 As[128*64];
    __shared__ __bf16 Bs[256*64];
    __shared__ float lstat[2][2][256];

    const int tid  = threadIdx.x;
    const int lane = tid & 63;
    const int wave = tid >> 6;
    const int wr = wave >> 1, wc = wave & 1;
    const int nwg   = (int)gridDim.x;
    const int chunk = nwg >> 3;
    const int bi    = (int)blockIdx.x;
    const int li    = (bi & 7) * chunk + (bi >> 3);
    const int m0    = (li >> LOGNB) * 128;
    const int n0    = (li & ((1 << LOGNB) - 1)) * 256;
    const int srow = tid >> 3, sslot = tid & 7;

    v4f acc[4][8];
    #pragma unroll
    for (int i=0;i<4;i++)
      #pragma unroll
      for (int j=0;j<8;j++) acc[i][j] = (v4f)(0.0f);

    v8bf ra[4], rb[8];
    auto loadAB = [&](int kb){
        float4 s0{}, s1{}, h0{}, h1{};
        if constexpr (BNA) {
            int kk = kb + sslot*8;
            s0 = *(const float4*)(scA + kk);
            s1 = *(const float4*)(scA + kk + 4);
            h0 = *(const float4*)(shA + kk);
            h1 = *(const float4*)(shA + kk + 4);
        }
        #pragma unroll
        for (int i=0;i<4;i++){
            int r = i*32 + srow;
            v8bf v = *(const v8bf*)(A + (size_t)(m0+r)*K + kb + sslot*8);
            if constexpr (BNA) v = bn_relu8(v, s0, s1, h0, h1);
            ra[i] = v;
        }
        #pragma unroll
        for (int i=0;i<8;i++){
            int r = i*32 + srow;
            rb[i] = *(const v8bf*)(Bw + (size_t)(n0+r)*K + kb + sslot*8);
        }
    };

    loadAB(0);

    for (int k0 = 0; k0 < K; k0 += 64) {
        __syncthreads();
        #pragma unroll
        for (int i=0;i<4;i++){
            int r = i*32 + srow;
            int p = sslot ^ (r & 7);
            *(v8bf*)(&As[r*64 + p*8]) = ra[i];
        }
        #pragma unroll
        for (int i=0;i<8;i++){
            int r = i*32 + srow;
            int p = sslot ^ (r & 7);
            *(v8bf*)(&Bs[r*64 + p*8]) = rb[i];
        }
        __syncthreads();
        if (k0 + 64 < K) loadAB(k0 + 64);
        #pragma unroll
        for (int kk = 0; kk < 2; ++kk) {
            v8bf af[4], bfr[8];
            #pragma unroll
            for (int i=0;i<4;i++){
                int arow = wr*64 + i*16 + (lane & 15);
                int sg = kk*4 + (lane >> 4);
                af[i] = *(const v8bf*)(&As[arow*64 + ((sg ^ (arow & 7))<<3)]);
            }
            #pragma unroll
            for (int j=0;j<8;j++){
                int brow = wc*128 + j*16 + (lane & 15);
                int sg = kk*4 + (lane >> 4);
                bfr[j] = *(const v8bf*)(&Bs[brow*64 + ((sg ^ (brow & 7))<<3)]);
            }
            #pragma unroll
            for (int i=0;i<4;i++)
              #pragma unroll
              for (int j=0;j<8;j++)
                acc[i][j] = __builtin_amdgcn_mfma_f32_16x16x32_bf16(af[i], bfr[j], acc[i][j], 0,0,0);
        }
    }

    const int b = m0 / RPB;
    const float* brow_ = bias + (size_t)b * bias_bstride;
    float colmax[8], csum[8], csq[8];
    #pragma unroll
    for (int j=0;j<8;j++){ colmax[j] = -3.402823466e38f; csum[j]=0.f; csq[j]=0.f; }

    #pragma unroll
    for (int i=0;i<4;i++){
        int rbase = m0 + wr*64 + i*16 + ((lane>>4)<<2);
        #pragma unroll
        for (int j=0;j<8;j++){
            int col = n0 + wc*128 + j*16 + (lane & 15);
            float bv = brow_[col];
            #pragma unroll
            for (int q=0;q<4;q++){
                float v = acc[i][j][q] + bv;
                if constexpr (STORE) Cout[(size_t)(rbase+q)*Nw + col] = (__bf16)v;
                if constexpr (DOMAX) colmax[j] = fmaxf(colmax[j], v);
                if constexpr (STATS) { csum[j] += v; csq[j] = fmaf(v,v,csq[j]); }
            }
        }
    }
    if constexpr (DOMAX) {
        #pragma unroll
        for (int j=0;j<8;j++){
            float v = colmax[j];
            v = fmaxf(v, __shfl_xor(v, 16));
            v = fmaxf(v, __shfl_xor(v, 32));
            if (lane < 16) {
                int col = n0 + wc*128 + j*16 + lane;
                atomicMax(&maxenc[(size_t)b*Nw + col], fenc(v));
            }
        }
    }
    if constexpr (STATS) {
        #pragma unroll
        for (int j=0;j<8;j++){
            float s = csum[j], q = csq[j];
            s += __shfl_xor(s, 16); s += __shfl_xor(s, 32);
            q += __shfl_xor(q, 16); q += __shfl_xor(q, 32);
            if (lane < 16) {
                int c = wc*128 + j*16 + lane;
                lstat[0][wr][c] = s;
                lstat[1][wr][c] = q;
            }
        }
        __syncthreads();
        if (tid < 256) {
            float s = lstat[0][0][tid] + lstat[0][1][tid];
            float q = lstat[1][0][tid] + lstat[1][1][tid];
            atomicAdd(&gsum[n0 + tid], s);
            atomicAdd(&gsq [n0 + tid], q);
        }
    }
}

// ---------------- bias3[b][d] = b3[d] + fg[b] @ W3[:, :256]^T
__global__ __launch_bounds__(256) void bias3_k(const unsigned* __restrict__ fge,
        const float* __restrict__ W3, const float* __restrict__ b3,
        float* __restrict__ bias3)
{
    int b = blockIdx.x, tid = threadIdx.x;
    __shared__ float fg[256];
    fg[tid] = fdec(fge[b*256 + tid]);
    __syncthreads();
    for (int d = tid; d < 512; d += 256) {
        const float* wrow = W3 + (size_t)d*512;
        float s = b3[d];
        for (int c = 0; c < 256; c += 4) {
            s = fmaf(fg[c+0], wrow[c+0], s);
            s = fmaf(fg[c+1], wrow[c+1], s);
            s = fmaf(fg[c+2], wrow[c+2], s);
            s = fmaf(fg[c+3], wrow[c+3], s);
        }
        bias3[b*512 + d] = s;
    }
}

__global__ void decode_k(const unsigned* __restrict__ enc, float* __restrict__ feat)
{
    int i = blockIdx.x*256 + threadIdx.x;
    int b = i >> 10, c = i & 1023;
    feat[(size_t)b*2048 + c] = fdec(enc[i]);
}

__global__ __launch_bounds__(256) void gates_k(
        const float* __restrict__ Wf, const float* __restrict__ bfv,
        const float* __restrict__ Wi, const float* __restrict__ biv,
        const float* __restrict__ Wo, const float* __restrict__ bov,
        const float* __restrict__ Wc, const float* __restrict__ bcv,
        const float* __restrict__ memv, float* __restrict__ feat)
{
    int tid = threadIdx.x;
    int b = tid & 15;
    int j = blockIdx.x*16 + (tid >> 4);
    const float* x  = feat + (size_t)b*2048;
    const float* rf = Wf + (size_t)j*1024;
    const float* ri = Wi + (size_t)j*1024;
    const float* ro = Wo + (size_t)j*1024;
    const float* rc = Wc + (size_t)j*1024;
    float sf = bfv[j], si = biv[j], so = bov[j], scn = bcv[j];
    for (int c = 0; c < 1024; c += 4) {
        float4 xv = *(const float4*)(x + c);
        float4 a  = *(const float4*)(rf + c);
        sf = fmaf(xv.x,a.x, fmaf(xv.y,a.y, fmaf(xv.z,a.z, fmaf(xv.w,a.w, sf))));
        float4 bq = *(const float4*)(ri + c);
        si = fmaf(xv.x,bq.x, fmaf(xv.y,bq.y, fmaf(xv.z,bq.z, fmaf(xv.w,bq.w, si))));
        float4 cq = *(const float4*)(ro + c);
        so = fmaf(xv.x,cq.x, fmaf(xv.y,cq.y, fmaf(xv.z,cq.z, fmaf(xv.w,cq.w, so))));
        float4 dq = *(const float4*)(rc + c);
        scn= fmaf(xv.x,dq.x, fmaf(xv.y,dq.y, fmaf(xv.z,dq.z, fmaf(xv.w,dq.w, scn))));
    }
    float fg = 1.f/(1.f + expf(-sf));
    float ig = 1.f/(1.f + expf(-si));
    float og = 1.f/(1.f + expf(-so));
    float cd = tanhf(scn);
    float h  = og * tanhf(fmaf(fg, memv[j], ig*cd));
    feat[(size_t)b*2048 + 1024 + j] = h;
}

// ---------------- batched decoder (R6-proven): 16 rows staged in LDS;
// each W row read ONCE. 8 cols/block (2/wave).
template<bool RELU>
__global__ __launch_bounds__(256) void dec2_k(const float* __restrict__ in,
        const float* __restrict__ W, const float* __restrict__ bias,
        float* __restrict__ out, int N)
{
    __shared__ float xin[16*2048];
    int tid = threadIdx.x;
    for (int i = tid; i < 8192; i += 256)
        *(float4*)&xin[i*4] = *(const float4*)&in[i*4];
    __syncthreads();
    int lane = tid & 63, wv = tid >> 6;
    #pragma unroll
    for (int c = 0; c < 2; ++c) {
        int col = blockIdx.x*8 + wv*2 + c;
        const float* wrow = W + (size_t)col*2048;
        float s[16];
        #pragma unroll
        for (int b=0;b<16;b++) s[b]=0.f;
        #pragma unroll
        for (int it = 0; it < 8; ++it) {
            int k = it*256 + lane*4;
            float4 w4 = *(const float4*)(wrow + k);
            #pragma unroll
            for (int b=0;b<16;b++){
                const float* xb = &xin[b*2048 + k];
                s[b] = fmaf(w4.x, xb[0], fmaf(w4.y, xb[1], fmaf(w4.z, xb[2], fmaf(w4.w, xb[3], s[b]))));
            }
        }
        #pragma unroll
        for (int off=32; off; off>>=1){
            #pragma unroll
            for (int b=0;b<16;b++) s[b] += __shfl_xor(s[b], off);
        }
        if (lane == 0) {
            float bv = bias[col];
            #pragma unroll
            for (int b=0;b<16;b++){
                float v = s[b] + bv;
                if (RELU) v = fmaxf(v, 0.f);
                out[(size_t)b*N + col] = v;
            }
        }
    }
}

extern "C" void kernel_launch(void* const* d_in, const int* in_sizes, int n_in,
                              void* d_out, int out_size, void* d_ws, size_t ws_size,
                              hipStream_t stream)
{
    (void)in_sizes; (void)n_in; (void)out_size; (void)ws_size;
    const float* partial = (const float*)d_in[0];
    const float* W1 = (const float*)d_in[1];
    const float* b1 = (const float*)d_in[2];
    const float* g1 = (const float*)d_in[3];
    const float* be1= (const float*)d_in[4];
    const float* W2 = (const float*)d_in[5];
    const float* b2 = (const float*)d_in[6];
    const float* W3 = (const float*)d_in[7];
    const float* b3 = (const float*)d_in[8];
    const float* g2 = (const float*)d_in[9];
    const float* be2= (const float*)d_in[10];
    const float* W4 = (const float*)d_in[11];
    const float* b4 = (const float*)d_in[12];
    const float* Wf = (const float*)d_in[13];
    const float* bfv= (const float*)d_in[14];
    const float* Wi = (const float*)d_in[15];
    const float* biv= (const float*)d_in[16];
    const float* Wo = (const float*)d_in[17];
    const float* bov= (const float*)d_in[18];
    const float* Wc = (const float*)d_in[19];
    const float* bcv= (const float*)d_in[20];
    const float* memv=(const float*)d_in[21];
    const float* D1w= (const float*)d_in[22];
    const float* D1b= (const float*)d_in[23];
    const float* D2w= (const float*)d_in[24];
    const float* D2b= (const float*)d_in[25];
    const float* D3w= (const float*)d_in[26];
    const float* D3b= (const float*)d_in[27];
    const float* D4w= (const float*)d_in[28];
    const float* D4b= (const float*)d_in[29];

    char* w = (char*)d_ws;
    size_t off = 0;
    auto alloc = [&](size_t bytes) -> void* {
        void* p = w + off; off += (bytes + 255) & ~(size_t)255; return p;
    };
    __bf16* y1bn = (__bf16*)alloc((size_t)NPTS*128*2);
    __bf16* f2   = (__bf16*)alloc((size_t)NPTS*256*2);
    __bf16* y3   = (__bf16*)alloc((size_t)NPTS*512*2);   // PRE-BN y3
    __bf16* W2b  = (__bf16*)alloc(256*128*2);
    __bf16* W3bb = (__bf16*)alloc(512*256*2);
    __bf16* W4b  = (__bf16*)alloc(1024*512*2);
    char* accbase = (char*)(w + off);
    float* gsum1    = (float*)alloc(128*4);
    float* gsumsq1  = (float*)alloc(128*4);
    float* gsum3    = (float*)alloc(512*4);
    float* gsumsq3  = (float*)alloc(512*4);
    unsigned* fg_enc    = (unsigned*)alloc(16*256*4);
    unsigned* featg_enc = (unsigned*)alloc(16*1024*4);
    size_t accbytes = (size_t)((w + off) - accbase);
    float* scale1 = (float*)alloc(128*4);
    float* shift1 = (float*)alloc(128*4);
    float* scale3 = (float*)alloc(512*4);
    float* shift3 = (float*)alloc(512*4);
    float* bias3  = (float*)alloc(16*512*4);
    float* feat   = (float*)alloc(16*2048*4);
    float* z1     = (float*)alloc(16*2048*4);
    float* z2     = (float*)alloc(16*2048*4);
    float* z3     = (float*)alloc(16*2048*4);

    hipMemsetAsync(accbase, 0, accbytes, stream);

    cvt_k<<<dim3(128), 256, 0, stream>>>(W2, W2b, 256, 128, 128, 0);
    cvt_k<<<dim3(512), 256, 0, stream>>>(W3, W3bb, 512, 256, 512, 256);
    cvt_k<<<dim3(2048),256, 0, stream>>>(W4, W4b, 1024, 512, 512, 0);

    stats1_k<<<dim3(256), 256, 0, stream>>>(partial, W1, b1, gsum1, gsumsq1);
    finalize_k<<<dim3(1), 128, 0, stream>>>(gsum1, gsumsq1, g1, be1, scale1, shift1, 128, 1.f/NPTS);
    apply1_k<<<dim3(8192), 256, 0, stream>>>(partial, W1, b1, scale1, shift1, y1bn);

    // stage B: f2 = y1bn @ W2^T + b2 ; fg = per-batch colmax  (N=256 in one tile)
    gemm_k<true,true,false,false,0><<<dim3(1024), 256, 0, stream>>>(
        y1bn, W2b, 128, 256, b2, 0, f2, fg_enc, nullptr, nullptr, nullptr, nullptr);

    bias3_k<<<dim3(16), 256, 0, stream>>>(fg_enc, W3, b3, bias3);

    // stage C: y3 = f2 @ W3[:,256:]^T + bias3[b]  (+ fused BN2 stats)
    gemm_k<true,false,true,false,1><<<dim3(2048), 256, 0, stream>>>(
        f2, W3bb, 256, 512, bias3, 512, y3, nullptr, gsum3, gsumsq3, nullptr, nullptr);

    finalize_k<<<dim3(2), 256, 0, stream>>>(gsum3, gsumsq3, g2, be2, scale3, shift3, 512, 1.f/NPTS);

    // stage D: feat_global = per-batch colmax( relu(bn2(y3)) @ W4^T + b4 )
    gemm_k<false,true,false,true,2><<<dim3(4096), 256, 0, stream>>>(
        y3, W4b, 512, 1024, b4, 0, nullptr, featg_enc, nullptr, nullptr, scale3, shift3);

    decode_k<<<dim3(64), 256, 0, stream>>>(featg_enc, feat);
    gates_k<<<dim3(64), 256, 0, stream>>>(Wf,bfv, Wi,biv, Wo,bov, Wc,bcv, memv, feat);

    // decoder: weight-read-once batched GEMV
    dec2_k<true ><<<dim3(256), 256, 0, stream>>>(feat, D1w, D1b, z1, 2048);
    dec2_k<true ><<<dim3(256), 256, 0, stream>>>(z1,   D2w, D2b, z2, 2048);
    dec2_k<true ><<<dim3(256), 256, 0, stream>>>(z2,   D3w, D3b, z3, 2048);
    dec2_k<false><<<dim3(768), 256, 0, stream>>>(z3,   D4w, D4b, (float*)d_out, 6144);
}

// Round 10
// 476.087 us; speedup vs baseline: 1.2671x; 1.0560x over previous
//
#include <hip/hip_runtime.h>
#include <hip/hip_bf16.h>

typedef __bf16 v8bf __attribute__((ext_vector_type(8)));
typedef float  v4f  __attribute__((ext_vector_type(4)));

#define NPTS (16*8192)
#define RPB  8192

// async global->LDS, 16B per lane; LDS dest is wave-uniform base + lane*16
#define GLOAD_LDS16(g, l) __builtin_amdgcn_global_load_lds( \
    (const __attribute__((address_space(1))) void*)(g), \
    (__attribute__((address_space(3))) void*)(l), 16, 0, 0)

__device__ __forceinline__ unsigned fenc(float x){
    unsigned u = __float_as_uint(x);
    return (u & 0x80000000u) ? ~u : (u | 0x80000000u);
}
__device__ __forceinline__ float fdec(unsigned u){
    return __uint_as_float((u & 0x80000000u) ? (u ^ 0x80000000u) : ~u);
}

__device__ __forceinline__ v8bf bn_relu8(v8bf v, float4 s0, float4 s1, float4 h0, float4 h1){
    v8bf r;
    r[0] = (__bf16)fmaxf(fmaf((float)v[0], s0.x, h0.x), 0.f);
    r[1] = (__bf16)fmaxf(fmaf((float)v[1], s0.y, h0.y), 0.f);
    r[2] = (__bf16)fmaxf(fmaf((float)v[2], s0.z, h0.z), 0.f);
    r[3] = (__bf16)fmaxf(fmaf((float)v[3], s0.w, h0.w), 0.f);
    r[4] = (__bf16)fmaxf(fmaf((float)v[4], s1.x, h1.x), 0.f);
    r[5] = (__bf16)fmaxf(fmaf((float)v[5], s1.y, h1.y), 0.f);
    r[6] = (__bf16)fmaxf(fmaf((float)v[6], s1.z, h1.z), 0.f);
    r[7] = (__bf16)fmaxf(fmaf((float)v[7], s1.w, h1.w), 0.f);
    return r;
}

// ---------------- stage A
__global__ __launch_bounds__(256) void stats1_k(const float* __restrict__ P,
        const float* __restrict__ W1, const float* __restrict__ b1,
        float* __restrict__ gsum, float* __restrict__ gsumsq)
{
    int tid = threadIdx.x;
    int c = tid & 127, half = tid >> 7;
    float w0 = W1[c*3+0], w1 = W1[c*3+1], w2 = W1[c*3+2], bb = b1[c];
    float s = 0.f, s2 = 0.f;
    int base = blockIdx.x * 512 + half;
    for (int i = 0; i < 256; ++i) {
        int p = base + i*2;
        float x = P[p*3+0], y = P[p*3+1], z = P[p*3+2];
        float v = fmaf(w0,x, fmaf(w1,y, fmaf(w2,z, bb)));
        s += v; s2 = fmaf(v,v,s2);
    }
    __shared__ float ls[256], lq[256];
    ls[tid] = s; lq[tid] = s2;
    __syncthreads();
    if (half == 0) {
        atomicAdd(&gsum[c],   s  + ls[tid+128]);
        atomicAdd(&gsumsq[c], s2 + lq[tid+128]);
    }
}

__global__ void finalize_k(const float* __restrict__ gsum, const float* __restrict__ gsumsq,
        const float* __restrict__ gamma, const float* __restrict__ beta,
        float* __restrict__ scale, float* __restrict__ shift, int C, float invn)
{
    int c = blockIdx.x*blockDim.x + threadIdx.x;
    if (c >= C) return;
    float m   = gsum[c]*invn;
    float var = fmaxf(gsumsq[c]*invn - m*m, 0.f);
    float rs  = rsqrtf(var + 1e-5f);
    float sc  = gamma[c]*rs;
    scale[c] = sc;
    shift[c] = beta[c] - m*sc;
}

__global__ __launch_bounds__(256) void apply1_k(const float* __restrict__ P,
        const float* __restrict__ W1, const float* __restrict__ b1,
        const float* __restrict__ sc, const float* __restrict__ sh,
        __bf16* __restrict__ out)
{
    int tid = threadIdx.x;
    int c = tid & 127, ph = tid >> 7;
    float w0 = W1[c*3+0], w1 = W1[c*3+1], w2 = W1[c*3+2], bb = b1[c];
    float a = sc[c], b_ = sh[c];
    int base = blockIdx.x * 16 + ph;
    #pragma unroll
    for (int i = 0; i < 8; ++i) {
        int p = base + i*2;
        float x = P[p*3+0], y = P[p*3+1], z = P[p*3+2];
        float v = fmaf(w0,x, fmaf(w1,y, fmaf(w2,z, bb)));
        v = fmaxf(fmaf(v, a, b_), 0.f);
        out[(size_t)p*128 + c] = (__bf16)v;
    }
}

__global__ void cvt_k(const float* __restrict__ src, __bf16* __restrict__ dst,
                      int rows, int cols, int sstride, int coff)
{
    int i = blockIdx.x*256 + threadIdx.x;
    if (i >= rows*cols) return;
    int r = i / cols, c = i - r*cols;
    dst[i] = (__bf16)src[(size_t)r*sstride + coff + c];
}

// ---------------- 128x256 MFMA GEMM — R8 sync structure; staging via
// global_load_lds with pre-swizzled global source (LDS stays linear; the
// source permutation equals the ds_read swizzle involution). A goes through
// registers only when BNA (BN-apply fused).
template<bool STORE, bool DOMAX, bool STATS, bool BNA, int LOGNB>
__global__ __launch_bounds__(256, 2) void gemm_k(
        const __bf16* __restrict__ A, const __bf16* __restrict__ Bw,
        int K, int Nw,
        const float* __restrict__ bias, int bias_bstride,
        __bf16* __restrict__ Cout, unsigned* __restrict__ maxenc,
        float* __restrict__ gsum, float* __restrict__ gsq,
        const float* __restrict__ scA, const float* __restrict__ shA)
{
    __shared__ __bf16 As[128*64];
    __shared__ __bf16 Bs[256*64];
    __shared__ float lstat[2][2][256];

    const int tid  = threadIdx.x;
    const int lane = tid & 63;
    const int wave = tid >> 6;
    const int wr = wave >> 1, wc = wave & 1;
    const int nwg   = (int)gridDim.x;
    const int chunk = nwg >> 3;
    const int bi    = (int)blockIdx.x;
    const int li    = (bi & 7) * chunk + (bi >> 3);
    const int m0    = (li >> LOGNB) * 128;
    const int n0    = (li & ((1 << LOGNB) - 1)) * 256;
    const int srow = tid >> 3, sslot = tid & 7;
    // gload_lds geometry: lane covers row lrow of an 8-row stripe, 16B slot lslot;
    // pre-swizzled source column slot = lslot ^ lrow (constant per lane).
    const int lrow  = lane >> 3;
    const int swz   = ((lane & 7) ^ lrow) * 8;

    v4f acc[4][8];
    #pragma unroll
    for (int i=0;i<4;i++)
      #pragma unroll
      for (int j=0;j<8;j++) acc[i][j] = (v4f)(0.0f);

    v8bf ra[4];
    auto loadA_bn = [&](int kb){            // BNA: A->reg with BN+ReLU
        int kk = kb + sslot*8;
        float4 s0 = *(const float4*)(scA + kk);
        float4 s1 = *(const float4*)(scA + kk + 4);
        float4 h0 = *(const float4*)(shA + kk);
        float4 h1 = *(const float4*)(shA + kk + 4);
        #pragma unroll
        for (int i=0;i<4;i++){
            int r = i*32 + srow;
            v8bf v = *(const v8bf*)(A + (size_t)(m0+r)*K + kb + sslot*8);
            ra[i] = bn_relu8(v, s0, s1, h0, h1);
        }
    };
    auto stageB = [&](int kb){              // 8 insts/wave x 4 waves = 32KB
        #pragma unroll
        for (int j=0;j<8;j++){
            int r0 = (wave*8 + j)*8;
            GLOAD_LDS16(Bw + (size_t)(n0 + r0 + lrow)*K + kb + swz, &Bs[r0*64]);
        }
    };
    auto stageA = [&](int kb){              // 4 insts/wave x 4 waves = 16KB
        #pragma unroll
        for (int j=0;j<4;j++){
            int r0 = (wave*4 + j)*8;
            GLOAD_LDS16(A + (size_t)(m0 + r0 + lrow)*K + kb + swz, &As[r0*64]);
        }
    };

    if constexpr (BNA) loadA_bn(0);

    for (int k0 = 0; k0 < K; k0 += 64) {
        __syncthreads();                    // all reads of LDS done
        stageB(k0);
        if constexpr (BNA) {
            #pragma unroll
            for (int i=0;i<4;i++){
                int r = i*32 + srow;
                *(v8bf*)(&As[r*64 + ((sslot ^ (r & 7))<<3)]) = ra[i];
            }
        } else {
            stageA(k0);
        }
        __syncthreads();                    // drains vmcnt+lgkm: tile in LDS
        if constexpr (BNA) { if (k0 + 64 < K) loadA_bn(k0 + 64); }  // full phase of slack
        #pragma unroll
        for (int kk = 0; kk < 2; ++kk) {
            v8bf af[4], bfr[8];
            #pragma unroll
            for (int i=0;i<4;i++){
                int arow = wr*64 + i*16 + (lane & 15);
                int sg = kk*4 + (lane >> 4);
                af[i] = *(const v8bf*)(&As[arow*64 + ((sg ^ (arow & 7))<<3)]);
            }
            #pragma unroll
            for (int j=0;j<8;j++){
                int brow = wc*128 + j*16 + (lane & 15);
                int sg = kk*4 + (lane >> 4);
                bfr[j] = *(const v8bf*)(&Bs[brow*64 + ((sg ^ (brow & 7))<<3)]);
            }
            #pragma unroll
            for (int i=0;i<4;i++)
              #pragma unroll
              for (int j=0;j<8;j++)
                acc[i][j] = __builtin_amdgcn_mfma_f32_16x16x32_bf16(af[i], bfr[j], acc[i][j], 0,0,0);
        }
    }

    const int b = m0 / RPB;
    const float* brow_ = bias + (size_t)b * bias_bstride;
    float colmax[8], csum[8], csq[8];
    #pragma unroll
    for (int j=0;j<8;j++){ colmax[j] = -3.402823466e38f; csum[j]=0.f; csq[j]=0.f; }

    #pragma unroll
    for (int i=0;i<4;i++){
        int rbase = m0 + wr*64 + i*16 + ((lane>>4)<<2);
        #pragma unroll
        for (int j=0;j<8;j++){
            int col = n0 + wc*128 + j*16 + (lane & 15);
            float bv = brow_[col];
            #pragma unroll
            for (int q=0;q<4;q++){
                float v = acc[i][j][q] + bv;
                if constexpr (STORE) Cout[(size_t)(rbase+q)*Nw + col] = (__bf16)v;
                if constexpr (DOMAX) colmax[j] = fmaxf(colmax[j], v);
                if constexpr (STATS) { csum[j] += v; csq[j] = fmaf(v,v,csq[j]); }
            }
        }
    }
    if constexpr (DOMAX) {
        #pragma unroll
        for (int j=0;j<8;j++){
            float v = colmax[j];
            v = fmaxf(v, __shfl_xor(v, 16));
            v = fmaxf(v, __shfl_xor(v, 32));
            if (lane < 16) {
                int col = n0 + wc*128 + j*16 + lane;
                atomicMax(&maxenc[(size_t)b*Nw + col], fenc(v));
            }
        }
    }
    if constexpr (STATS) {
        #pragma unroll
        for (int j=0;j<8;j++){
            float s = csum[j], q = csq[j];
            s += __shfl_xor(s, 16); s += __shfl_xor(s, 32);
            q += __shfl_xor(q, 16); q += __shfl_xor(q, 32);
            if (lane < 16) {
                int c = wc*128 + j*16 + lane;
                lstat[0][wr][c] = s;
                lstat[1][wr][c] = q;
            }
        }
        __syncthreads();
        if (tid < 256) {
            float s = lstat[0][0][tid] + lstat[0][1][tid];
            float q = lstat[1][0][tid] + lstat[1][1][tid];
            atomicAdd(&gsum[n0 + tid], s);
            atomicAdd(&gsq [n0 + tid], q);
        }
    }
}

// ---------------- bias3[b][d] = b3[d] + fg[b] @ W3[:, :256]^T
__global__ __launch_bounds__(256) void bias3_k(const unsigned* __restrict__ fge,
        const float* __restrict__ W3, const float* __restrict__ b3,
        float* __restrict__ bias3)
{
    int b = blockIdx.x, tid = threadIdx.x;
    __shared__ float fg[256];
    fg[tid] = fdec(fge[b*256 + tid]);
    __syncthreads();
    for (int d = tid; d < 512; d += 256) {
        const float* wrow = W3 + (size_t)d*512;
        float s = b3[d];
        for (int c = 0; c < 256; c += 4) {
            s = fmaf(fg[c+0], wrow[c+0], s);
            s = fmaf(fg[c+1], wrow[c+1], s);
            s = fmaf(fg[c+2], wrow[c+2], s);
            s = fmaf(fg[c+3], wrow[c+3], s);
        }
        bias3[b*512 + d] = s;
    }
}

__global__ void decode_k(const unsigned* __restrict__ enc, float* __restrict__ feat)
{
    int i = blockIdx.x*256 + threadIdx.x;
    int b = i >> 10, c = i & 1023;
    feat[(size_t)b*2048 + c] = fdec(enc[i]);
}

__global__ __launch_bounds__(256) void gates_k(
        const float* __restrict__ Wf, const float* __restrict__ bfv,
        const float* __restrict__ Wi, const float* __restrict__ biv,
        const float* __restrict__ Wo, const float* __restrict__ bov,
        const float* __restrict__ Wc, const float* __restrict__ bcv,
        const float* __restrict__ memv, float* __restrict__ feat)
{
    int tid = threadIdx.x;
    int b = tid & 15;
    int j = blockIdx.x*16 + (tid >> 4);
    const float* x  = feat + (size_t)b*2048;
    const float* rf = Wf + (size_t)j*1024;
    const float* ri = Wi + (size_t)j*1024;
    const float* ro = Wo + (size_t)j*1024;
    const float* rc = Wc + (size_t)j*1024;
    float sf = bfv[j], si = biv[j], so = bov[j], scn = bcv[j];
    for (int c = 0; c < 1024; c += 4) {
        float4 xv = *(const float4*)(x + c);
        float4 a  = *(const float4*)(rf + c);
        sf = fmaf(xv.x,a.x, fmaf(xv.y,a.y, fmaf(xv.z,a.z, fmaf(xv.w,a.w, sf))));
        float4 bq = *(const float4*)(ri + c);
        si = fmaf(xv.x,bq.x, fmaf(xv.y,bq.y, fmaf(xv.z,bq.z, fmaf(xv.w,bq.w, si))));
        float4 cq = *(const float4*)(ro + c);
        so = fmaf(xv.x,cq.x, fmaf(xv.y,cq.y, fmaf(xv.z,cq.z, fmaf(xv.w,cq.w, so))));
        float4 dq = *(const float4*)(rc + c);
        scn= fmaf(xv.x,dq.x, fmaf(xv.y,dq.y, fmaf(xv.z,dq.z, fmaf(xv.w,dq.w, scn))));
    }
    float fg = 1.f/(1.f + expf(-sf));
    float ig = 1.f/(1.f + expf(-si));
    float og = 1.f/(1.f + expf(-so));
    float cd = tanhf(scn);
    float h  = og * tanhf(fmaf(fg, memv[j], ig*cd));
    feat[(size_t)b*2048 + 1024 + j] = h;
}

// ---------------- batched decoder: 16 rows (128KB) staged in LDS via
// gload_lds: 128 insts x 1KB (32 per wave). Each W row read ONCE.
template<bool RELU>
__global__ __launch_bounds__(256) void dec2_k(const float* __restrict__ in,
        const float* __restrict__ W, const float* __restrict__ bias,
        float* __restrict__ out, int N)
{
    __shared__ float xin[16*2048];
    int tid = threadIdx.x;
    int lane = tid & 63, wv = tid >> 6;
    #pragma unroll
    for (int j = 0; j < 32; ++j) {
        int blk = wv*32 + j;                 // 0..127, each covers 256 floats
        GLOAD_LDS16(in + blk*256 + lane*4, &xin[blk*256]);
    }
    __syncthreads();
    #pragma unroll
    for (int c = 0; c < 2; ++c) {
        int col = blockIdx.x*8 + wv*2 + c;
        const float* wrow = W + (size_t)col*2048;
        float s[16];
        #pragma unroll
        for (int b=0;b<16;b++) s[b]=0.f;
        #pragma unroll
        for (int it = 0; it < 8; ++it) {
            int k = it*256 + lane*4;
            float4 w4 = *(const float4*)(wrow + k);
            #pragma unroll
            for (int b=0;b<16;b++){
                const float* xb = &xin[b*2048 + k];
                s[b] = fmaf(w4.x, xb[0], fmaf(w4.y, xb[1], fmaf(w4.z, xb[2], fmaf(w4.w, xb[3], s[b]))));
            }
        }
        #pragma unroll
        for (int off=32; off; off>>=1){
            #pragma unroll
            for (int b=0;b<16;b++) s[b] += __shfl_xor(s[b], off);
        }
        if (lane == 0) {
            float bv = bias[col];
            #pragma unroll
            for (int b=0;b<16;b++){
                float v = s[b] + bv;
                if (RELU) v = fmaxf(v, 0.f);
                out[(size_t)b*N + col] = v;
            }
        }
    }
}

extern "C" void kernel_launch(void* const* d_in, const int* in_sizes, int n_in,
                              void* d_out, int out_size, void* d_ws, size_t ws_size,
                              hipStream_t stream)
{
    (void)in_sizes; (void)n_in; (void)out_size; (void)ws_size;
    const float* partial = (const float*)d_in[0];
    const float* W1 = (const float*)d_in[1];
    const float* b1 = (const float*)d_in[2];
    const float* g1 = (const float*)d_in[3];
    const float* be1= (const float*)d_in[4];
    const float* W2 = (const float*)d_in[5];
    const float* b2 = (const float*)d_in[6];
    const float* W3 = (const float*)d_in[7];
    const float* b3 = (const float*)d_in[8];
    const float* g2 = (const float*)d_in[9];
    const float* be2= (const float*)d_in[10];
    const float* W4 = (const float*)d_in[11];
    const float* b4 = (const float*)d_in[12];
    const float* Wf = (const float*)d_in[13];
    const float* bfv= (const float*)d_in[14];
    const float* Wi = (const float*)d_in[15];
    const float* biv= (const float*)d_in[16];
    const float* Wo = (const float*)d_in[17];
    const float* bov= (const float*)d_in[18];
    const float* Wc = (const float*)d_in[19];
    const float* bcv= (const float*)d_in[20];
    const float* memv=(const float*)d_in[21];
    const float* D1w= (const float*)d_in[22];
    const float* D1b= (const float*)d_in[23];
    const float* D2w= (const float*)d_in[24];
    const float* D2b= (const float*)d_in[25];
    const float* D3w= (const float*)d_in[26];
    const float* D3b= (const float*)d_in[27];
    const float* D4w= (const float*)d_in[28];
    const float* D4b= (const float*)d_in[29];

    char* w = (char*)d_ws;
    size_t off = 0;
    auto alloc = [&](size_t bytes) -> void* {
        void* p = w + off; off += (bytes + 255) & ~(size_t)255; return p;
    };
    __bf16* y1bn = (__bf16*)alloc((size_t)NPTS*128*2);
    __bf16* f2   = (__bf16*)alloc((size_t)NPTS*256*2);
    __bf16* y3   = (__bf16*)alloc((size_t)NPTS*512*2);   // PRE-BN y3
    __bf16* W2b  = (__bf16*)alloc(256*128*2);
    __bf16* W3bb = (__bf16*)alloc(512*256*2);
    __bf16* W4b  = (__bf16*)alloc(1024*512*2);
    char* accbase = (char*)(w + off);
    float* gsum1    = (float*)alloc(128*4);
    float* gsumsq1  = (float*)alloc(128*4);
    float* gsum3    = (float*)alloc(512*4);
    float* gsumsq3  = (float*)alloc(512*4);
    unsigned* fg_enc    = (unsigned*)alloc(16*256*4);
    unsigned* featg_enc = (unsigned*)alloc(16*1024*4);
    size_t accbytes = (size_t)((w + off) - accbase);
    float* scale1 = (float*)alloc(128*4);
    float* shift1 = (float*)alloc(128*4);
    float* scale3 = (float*)alloc(512*4);
    float* shift3 = (float*)alloc(512*4);
    float* bias3  = (float*)alloc(16*512*4);
    float* feat   = (float*)alloc(16*2048*4);
    float* z1     = (float*)alloc(16*2048*4);
    float* z2     = (float*)alloc(16*2048*4);
    float* z3     = (float*)alloc(16*2048*4);

    hipMemsetAsync(accbase, 0, accbytes, stream);

    cvt_k<<<dim3(128), 256, 0, stream>>>(W2, W2b, 256, 128, 128, 0);
    cvt_k<<<dim3(512), 256, 0, stream>>>(W3, W3bb, 512, 256, 512, 256);
    cvt_k<<<dim3(2048),256, 0, stream>>>(W4, W4b, 1024, 512, 512, 0);

    stats1_k<<<dim3(256), 256, 0, stream>>>(partial, W1, b1, gsum1, gsumsq1);
    finalize_k<<<dim3(1), 128, 0, stream>>>(gsum1, gsumsq1, g1, be1, scale1, shift1, 128, 1.f/NPTS);
    apply1_k<<<dim3(8192), 256, 0, stream>>>(partial, W1, b1, scale1, shift1, y1bn);

    // stage B: f2 = y1bn @ W2^T + b2 ; fg = per-batch colmax  (N=256 in one tile)
    gemm_k<true,true,false,false,0><<<dim3(1024), 256, 0, stream>>>(
        y1bn, W2b, 128, 256, b2, 0, f2, fg_enc, nullptr, nullptr, nullptr, nullptr);

    bias3_k<<<dim3(16), 256, 0, stream>>>(fg_enc, W3, b3, bias3);

    // stage C: y3 = f2 @ W3[:,256:]^T + bias3[b]  (+ fused BN2 stats)
    gemm_k<true,false,true,false,1><<<dim3(2048), 256, 0, stream>>>(
        f2, W3bb, 256, 512, bias3, 512, y3, nullptr, gsum3, gsumsq3, nullptr, nullptr);

    finalize_k<<<dim3(2), 256, 0, stream>>>(gsum3, gsumsq3, g2, be2, scale3, shift3, 512, 1.f/NPTS);

    // stage D: feat_global = per-batch colmax( relu(bn2(y3)) @ W4^T + b4 )
    gemm_k<false,true,false,true,2><<<dim3(4096), 256, 0, stream>>>(
        y3, W4b, 512, 1024, b4, 0, nullptr, featg_enc, nullptr, nullptr, scale3, shift3);

    decode_k<<<dim3(64), 256, 0, stream>>>(featg_enc, feat);
    gates_k<<<dim3(64), 256, 0, stream>>>(Wf,bfv, Wi,biv, Wo,bov, Wc,bcv, memv, feat);

    // decoder: weight-read-once batched GEMV
    dec2_k<true ><<<dim3(256), 256, 0, stream>>>(feat, D1w, D1b, z1, 2048);
    dec2_k<true ><<<dim3(256), 256, 0, stream>>>(z1,   D2w, D2b, z2, 2048);
    dec2_k<true ><<<dim3(256), 256, 0, stream>>>(z2,   D3w, D3b, z3, 2048);
    dec2_k<false><<<dim3(768), 256, 0, stream>>>(z3,   D4w, D4b, (float*)d_out, 6144);
}